// Round 9
// baseline (253.419 us; speedup 1.0000x reference)
//
#include <hip/hip_runtime.h>

#define KDIM 4096
#define NDIM 4096
#define BM 128
#define BN 256
#define BK 64             // K bytes (int8) per tile
#define NTILE (KDIM / BK) // 64
#define BBUF 16384        // B tile: 256 rows x 64 B
#define NBUF 3

using i32x4 = __attribute__((ext_vector_type(4))) int;

__device__ __forceinline__ void g2l16(const void* g, void* l) {
  __builtin_amdgcn_global_load_lds(
      (const __attribute__((address_space(1))) void*)g,
      (__attribute__((address_space(3))) void*)l,
      16, 0, 0);
}

// ---------------- detect: weight buffer int32-expanded (flag=1) or raw int8 (flag=0)?
__global__ void w8l_detect(const int* __restrict__ w32, int* __restrict__ flag) {
  __shared__ int s;
  const int t = threadIdx.x;
  if (t == 0) s = 1;
  __syncthreads();
  bool oob = false;
#pragma unroll
  for (int i = 0; i < 16; ++i) {
    int v = w32[t * 16 + i];
    if (v < -128 || v > 127) oob = true;
  }
  if (oob) atomicAnd(&s, 0);
  __syncthreads();
  if (t == 0) *flag = s;
}

// ---------------- pack int32 weights to int8 (no-op when flag==0)
__global__ void w8l_pack(const void* __restrict__ wsrc, const int* __restrict__ flag,
                         signed char* __restrict__ wq) {
  if (*flag == 0) return;
  const int t = blockIdx.x * blockDim.x + threadIdx.x;
  const int4* s = (const int4*)wsrc;
  int4 a = s[t * 4 + 0], b = s[t * 4 + 1], c = s[t * 4 + 2], d = s[t * 4 + 3];
  int4 o;
  o.x = (a.x & 255) | ((a.y & 255) << 8) | ((a.z & 255) << 16) | ((a.w & 255) << 24);
  o.y = (b.x & 255) | ((b.y & 255) << 8) | ((b.z & 255) << 16) | ((b.w & 255) << 24);
  o.z = (c.x & 255) | ((c.y & 255) << 8) | ((c.z & 255) << 16) | ((c.w & 255) << 24);
  o.w = (d.x & 255) | ((d.y & 255) << 8) | ((d.z & 255) << 16) | ((d.w & 255) << 24);
  ((int4*)wq)[t] = o;
}

// ---------------- quantize activations: 16 floats / thread
__global__ void w8l_quant(const float* __restrict__ x, const float* __restrict__ xs,
                          signed char* __restrict__ xq) {
  const int t = blockIdx.x * blockDim.x + threadIdx.x;
  const float s = *xs;
  const float4* x4 = (const float4*)x;
  int4 o;
  int* op = (int*)&o;
#pragma unroll
  for (int q = 0; q < 4; ++q) {
    float4 f = x4[t * 4 + q];
    int v0 = __float2int_rn(f.x / s);
    int v1 = __float2int_rn(f.y / s);
    int v2 = __float2int_rn(f.z / s);
    int v3 = __float2int_rn(f.w / s);
    v0 = v0 < -128 ? -128 : (v0 > 127 ? 127 : v0);
    v1 = v1 < -128 ? -128 : (v1 > 127 ? 127 : v1);
    v2 = v2 < -128 ? -128 : (v2 > 127 ? 127 : v2);
    v3 = v3 < -128 ? -128 : (v3 > 127 ? 127 : v3);
    op[q] = (v0 & 255) | ((v1 & 255) << 8) | ((v2 & 255) << 16) | ((v3 & 255) << 24);
  }
  ((int4*)xq)[t] = o;
}

// ---------------- 128x256 i8 GEMM: A direct global->VGPR (L2-hot, reg dbuf),
// B tri-buffered in LDS (48 KiB -> 2 blocks/CU). LDS demand (96 KB/pair-window
// = 1129 cyc) < MFMA (1306 cyc): MFMA-bound by construction.
// Per tile: vmcnt(4) [waits G(t)+A(t), keeps G(t+1)] -> BAR -> issue A(t+1)
// -> issue G(t+2) -> 8 ds_read -> lgkm(4) -> 16 MFMA -> lgkm(0) -> 16 MFMA.
// B LDS row = 64 B = 4 slots; LDS(r,c) = global chunk (c ^ ((r>>1)&3)).
__global__ __launch_bounds__(256, 2) void w8l_gemm(
    const signed char* __restrict__ Aq,
    const signed char* __restrict__ Wraw, const signed char* __restrict__ Wpk,
    const int* __restrict__ flag,
    const float* __restrict__ scale, const float* __restrict__ xscale,
    const float* __restrict__ bias, float* __restrict__ out, int nbn) {
  __shared__ signed char lds[NBUF * BBUF];  // 48 KiB

  const signed char* __restrict__ Wq = (*flag) ? Wpk : Wraw;

  const int tid = threadIdx.x;
  const int lane = tid & 63;
  const int wid = tid >> 6;  // 0..3
  const int wr = wid >> 1;   // 0..1 (64-row half of 128)
  const int wc = wid & 1;    // 0..1 (128-col half of 256)
  const int l15 = lane & 15;
  const int l4 = (lane >> 4) & 3;  // k-quarter

  // XCD-aware bijective swizzle (grid = 1024, divisible by 8); consecutive
  // swz on one XCD share bm -> A panel L2-hot per XCD.
  const int nwg = gridDim.x;
  const int cpx = nwg >> 3;
  const int bid = blockIdx.x;
  const int swz = (bid & 7) * cpx + (bid >> 3);
  const int bm = swz / nbn, bn = swz % nbn;
  const int m0 = bm * BM, n0 = bn * BN;

  // ---- B staging (one g2l16 issue = 4 KB = 64 rows x 64 B)
  const unsigned r_in = (unsigned)tid >> 2;  // 0..63
  const unsigned c16 = (unsigned)tid & 3;
  const unsigned swcol = ((c16 ^ ((r_in >> 1) & 3u)) << 4);
  const signed char* wgp = Wq + (size_t)(n0 + r_in) * KDIM + swcol;
  const unsigned ldsoff = (unsigned)tid * 16u;

#define ISSUE_B(t, buf)                                                      \
  do {                                                                       \
    const size_t koff_ = (size_t)(t) * BK;                                   \
    signed char* lb_ = lds + (unsigned)(buf) * BBUF + ldsoff;                \
    _Pragma("unroll") for (int u = 0; u < 4; ++u)                            \
      g2l16(wgp + (size_t)(u * 64) * KDIM + koff_, lb_ + u * 4096);          \
  } while (0)

  // ---- A direct: lane reads row m0+wr*64+mi*16+l15, k = t*64 + l4*16
  const signed char* agl = Aq + (size_t)(m0 + wr * 64 + l15) * KDIM + l4 * 16;

#define LOAD_A(dst, t)                                                       \
  _Pragma("unroll") for (int mi = 0; mi < 4; ++mi)                           \
      dst[mi] = *(const i32x4*)(agl + (size_t)mi * (16 * KDIM) + (t) * 64);

  // ---- B frag read constants: s(R+l15) = (l15>>1)&3 (R multiple of 16)
  const unsigned slotoff = (unsigned)((l4 ^ ((l15 >> 1) & 3)) << 4);
  const unsigned brow = (unsigned)((wc * 128 + l15) * 64) + slotoff;

  i32x4 acc[4][8] = {};
  i32x4 aE[4], aO[4], bf[8];

#define SB __builtin_amdgcn_sched_barrier(0)

  // one tile step; AC = current A frags, AN = next-tile A frags (loaded here)
#define TILE(t, AC, AN, DO_A, DO_G, bufr_, bufi_, VMC)                       \
  do {                                                                       \
    asm volatile("s_waitcnt vmcnt(" #VMC ")" ::: "memory");                  \
    __builtin_amdgcn_s_barrier();                                            \
    SB;                                                                      \
    if (DO_A) { LOAD_A(AN, (t) + 1); }                                       \
    SB;                                                                      \
    if (DO_G) ISSUE_B((t) + 2, bufi_);                                       \
    SB;                                                                      \
    {                                                                        \
      const signed char* base_ = lds + (unsigned)(bufr_)*BBUF;               \
      _Pragma("unroll") for (int nj = 0; nj < 8; ++nj)                       \
          bf[nj] = *(const i32x4*)(base_ + brow + nj * 1024);                \
    }                                                                        \
    SB;                                                                      \
    asm volatile("s_waitcnt lgkmcnt(4)" ::: "memory");                       \
    SB;                                                                      \
    __builtin_amdgcn_s_setprio(1);                                           \
    _Pragma("unroll") for (int mi = 0; mi < 4; ++mi)                         \
        _Pragma("unroll") for (int nj = 0; nj < 4; ++nj)                     \
            acc[mi][nj] = __builtin_amdgcn_mfma_i32_16x16x64_i8(             \
                AC[mi], bf[nj], acc[mi][nj], 0, 0, 0);                       \
    __builtin_amdgcn_s_setprio(0);                                           \
    SB;                                                                      \
    asm volatile("s_waitcnt lgkmcnt(0)" ::: "memory");                       \
    SB;                                                                      \
    __builtin_amdgcn_s_setprio(1);                                           \
    _Pragma("unroll") for (int mi = 0; mi < 4; ++mi)                         \
        _Pragma("unroll") for (int nj = 4; nj < 8; ++nj)                     \
            acc[mi][nj] = __builtin_amdgcn_mfma_i32_16x16x64_i8(             \
                AC[mi], bf[nj], acc[mi][nj], 0, 0, 0);                       \
    __builtin_amdgcn_s_setprio(0);                                           \
    SB;                                                                      \
  } while (0)

  // prologue — issue order G(0), A(0), G(1) matches steady-state queue
  ISSUE_B(0, 0);
  SB;
  LOAD_A(aE, 0);
  SB;
  ISSUE_B(1, 1);
  SB;

  int bufr = 0, bufi = 2;
#pragma unroll 1
  for (int t2 = 0; t2 < NTILE - 2; t2 += 2) {  // covers t = 0..61
    TILE(t2, aE, aO, 1, 1, bufr, bufi, 4);
    bufr = (bufr == 2) ? 0 : bufr + 1;
    bufi = (bufi == 2) ? 0 : bufi + 1;
    TILE(t2 + 1, aO, aE, 1, 1, bufr, bufi, 4);
    bufr = (bufr == 2) ? 0 : bufr + 1;
    bufi = (bufi == 2) ? 0 : bufi + 1;
  }
  // t = 62 (even -> uses aE, loads aO; no new staging), t = 63 (uses aO)
  TILE(62, aE, aO, 1, 0, bufr, bufi, 4);
  bufr = (bufr == 2) ? 0 : bufr + 1;
  bufi = (bufi == 2) ? 0 : bufi + 1;
  TILE(63, aO, aE, 0, 0, bufr, bufi, 0);

  // epilogue: C/D layout col=lane&15, row=(lane>>4)*4+reg [m89, dtype-indep]
  const float cs = scale[0] * xscale[0];
#pragma unroll
  for (int nj = 0; nj < 8; ++nj) {
    const int n = n0 + wc * 128 + nj * 16 + l15;
    const float bj = bias[n];
#pragma unroll
    for (int mi = 0; mi < 4; ++mi) {
      const int m = m0 + wr * 64 + mi * 16 + l4 * 4;
      float* o = out + (size_t)m * NDIM + n;
#pragma unroll
      for (int v = 0; v < 4; ++v)
        o[(size_t)v * NDIM] = (float)acc[mi][nj][v] * cs + bj;
    }
  }
#undef ISSUE_B
#undef LOAD_A
#undef TILE
#undef SB
}

extern "C" void kernel_launch(void* const* d_in, const int* in_sizes, int n_in,
                              void* d_out, int out_size, void* d_ws, size_t ws_size,
                              hipStream_t stream) {
  const float* x = (const float*)d_in[0];
  const void* w = d_in[1];
  const float* scale = (const float*)d_in[2];
  const float* xscale = (const float*)d_in[3];
  const float* bias = (const float*)d_in[4];
  float* out = (float*)d_out;

  const int M = in_sizes[0] / KDIM;  // 8192

  int* flag = (int*)d_ws;
  signed char* wq = (signed char*)d_ws + 256;
  signed char* aq = wq + (size_t)NDIM * KDIM;

  const size_t need = 256 + (size_t)NDIM * KDIM + (size_t)M * KDIM;
  if (ws_size < need) return;

  w8l_detect<<<1, 256, 0, stream>>>((const int*)w, flag);
  w8l_pack<<<(NDIM * KDIM / 16) / 256, 256, 0, stream>>>(w, flag, wq);
  w8l_quant<<<(M * KDIM / 16) / 256, 256, 0, stream>>>(x, xscale, aq);

  const int nbn = NDIM / BN;  // 16
  w8l_gemm<<<(M / BM) * nbn, 256, 0, stream>>>(
      aq, (const signed char*)w, wq, flag, scale, xscale, bias, out, nbn);
}

// Round 10
// 201.743 us; speedup vs baseline: 1.2561x; 1.2561x over previous
//
#include <hip/hip_runtime.h>

#define KDIM 4096
#define NDIM 4096
#define BM 256
#define BN 256
#define BK 128            // K bytes (int8) per tile
#define NTILE (KDIM / BK) // 32
#define BBUF 32768        // B tile: 256 rows x 128 B

using i32x4 = __attribute__((ext_vector_type(4))) int;

__device__ __forceinline__ void g2l16(const void* g, void* l) {
  __builtin_amdgcn_global_load_lds(
      (const __attribute__((address_space(1))) void*)g,
      (__attribute__((address_space(3))) void*)l,
      16, 0, 0);
}

// ---------------- detect: weight buffer int32-expanded (flag=1) or raw int8 (flag=0)?
__global__ void w8l_detect(const int* __restrict__ w32, int* __restrict__ flag) {
  __shared__ int s;
  const int t = threadIdx.x;
  if (t == 0) s = 1;
  __syncthreads();
  bool oob = false;
#pragma unroll
  for (int i = 0; i < 16; ++i) {
    int v = w32[t * 16 + i];
    if (v < -128 || v > 127) oob = true;
  }
  if (oob) atomicAnd(&s, 0);
  __syncthreads();
  if (t == 0) *flag = s;
}

// ---------------- pack int32 weights to int8 (no-op when flag==0)
__global__ void w8l_pack(const void* __restrict__ wsrc, const int* __restrict__ flag,
                         signed char* __restrict__ wq) {
  if (*flag == 0) return;
  const int t = blockIdx.x * blockDim.x + threadIdx.x;
  const int4* s = (const int4*)wsrc;
  int4 a = s[t * 4 + 0], b = s[t * 4 + 1], c = s[t * 4 + 2], d = s[t * 4 + 3];
  int4 o;
  o.x = (a.x & 255) | ((a.y & 255) << 8) | ((a.z & 255) << 16) | ((a.w & 255) << 24);
  o.y = (b.x & 255) | ((b.y & 255) << 8) | ((b.z & 255) << 16) | ((b.w & 255) << 24);
  o.z = (c.x & 255) | ((c.y & 255) << 8) | ((c.z & 255) << 16) | ((c.w & 255) << 24);
  o.w = (d.x & 255) | ((d.y & 255) << 8) | ((d.z & 255) << 16) | ((d.w & 255) << 24);
  ((int4*)wq)[t] = o;
}

// ---------------- quantize activations INTO MFMA FRAGMENT LAYOUT:
// A'[cell] where cell = (mb*256 + kc)*16 + r  (mb=m>>4, kc=k>>4, r=m&15), 16 B/cell.
// A wave's A-fragment (16 rows x one k-chunk x 16 B) = 1 KB CONTIGUOUS.
__global__ void w8l_quant(const float* __restrict__ x, const float* __restrict__ xs,
                          signed char* __restrict__ aq) {
  const int t = blockIdx.x * blockDim.x + threadIdx.x;  // cell index
  const float s = *xs;
  const int r = t & 15;
  const int kc = (t >> 4) & 255;
  const int mb = t >> 12;
  const float4* x4 = (const float4*)(x + (size_t)(mb * 16 + r) * KDIM + kc * 16);
  int4 o;
  int* op = (int*)&o;
#pragma unroll
  for (int q = 0; q < 4; ++q) {
    float4 f = x4[q];
    int v0 = __float2int_rn(f.x / s);
    int v1 = __float2int_rn(f.y / s);
    int v2 = __float2int_rn(f.z / s);
    int v3 = __float2int_rn(f.w / s);
    v0 = v0 < -128 ? -128 : (v0 > 127 ? 127 : v0);
    v1 = v1 < -128 ? -128 : (v1 > 127 ? 127 : v1);
    v2 = v2 < -128 ? -128 : (v2 > 127 ? 127 : v2);
    v3 = v3 < -128 ? -128 : (v3 > 127 ? 127 : v3);
    op[q] = (v0 & 255) | ((v1 & 255) << 8) | ((v2 & 255) << 16) | ((v3 & 255) << 24);
  }
  ((int4*)aq)[t] = o;
}

// ---------------- 256x256 i8 GEMM: A' direct global->VGPR (coalesced 1KB frag
// loads on the VMEM pipe — the pipe that measurably overlaps MFMA), B g2l-staged
// in double-buffered LDS (64 KiB). LDS traffic/tile: 64 KB reads + 32 KB writes
// (~1030 cyc) vs r4's 256 KB (~2800): the additive DS+MFMA sum shrinks.
// B LDS row = 128 B = 8 slots of 16 B; LDS(r,c) = global chunk (c ^ (r&7)).
__global__ __launch_bounds__(512, 2) void w8l_gemm(
    const signed char* __restrict__ Ap,
    const signed char* __restrict__ Wraw, const signed char* __restrict__ Wpk,
    const int* __restrict__ flag,
    const float* __restrict__ scale, const float* __restrict__ xscale,
    const float* __restrict__ bias, float* __restrict__ out, int nbn) {
  __shared__ signed char lds[2 * BBUF];  // 64 KiB

  const signed char* __restrict__ Wq = (*flag) ? Wpk : Wraw;

  const int tid = threadIdx.x;
  const int lane = tid & 63;
  const int wid = tid >> 6;  // 0..7
  const int wr = wid >> 2;   // 0..1 (wave rows: 128)
  const int wc = wid & 3;    // 0..3 (wave cols: 64)
  const int l15 = lane & 15;
  const int l4 = (lane >> 4) & 3;  // k-chunk quarter

  // XCD-aware bijective swizzle (grid = 512, divisible by 8)
  const int nwg = gridDim.x;
  const int cpx = nwg >> 3;
  const int bid = blockIdx.x;
  const int swz = (bid & 7) * cpx + (bid >> 3);
  const int bm = swz / nbn, bn = swz % nbn;
  const int m0 = bm * BM, n0 = bn * BN;

  // ---- B staging: one g2l16 issue = 512 thr x 16 B = 8 KB = 64 rows x 128 B
  const unsigned r_in = (unsigned)tid >> 3;  // 0..63
  const unsigned c16 = (unsigned)tid & 7;
  const unsigned swcol = ((c16 ^ (r_in & 7u)) << 4);
  const signed char* wgp = Wq + (size_t)(n0 + r_in) * KDIM + swcol;
  const unsigned ldsoff = (unsigned)tid * 16u;

#define ISSUE_B(t)                                                           \
  do {                                                                       \
    const size_t koff_ = (size_t)(t) * BK;                                   \
    signed char* lb_ = lds + (unsigned)((t) & 1) * BBUF + ldsoff;            \
    _Pragma("unroll") for (int u = 0; u < 4; ++u)                            \
      g2l16(wgp + (size_t)(u * 64) * KDIM + koff_, lb_ + u * 8192);          \
  } while (0)

  // ---- A' direct loads: frag (mi, ks) of tile t at
  //   Ap + (m0/16 + wr*8 + mi)*65536 + (t*8 + ks*4)*256 + l4*256 + l15*16
  const signed char* aglp =
      Ap + (size_t)(m0 / 16 + wr * 8) * 65536 + l4 * 256 + l15 * 16;

#define LOAD_A(dst, t, ks)                                                   \
  _Pragma("unroll") for (int mi = 0; mi < 8; ++mi)                           \
      dst[mi] = *(const i32x4*)(aglp + (size_t)mi * 65536 +                  \
                                (size_t)(t) * 2048 + (ks) * 1024);

  // ---- B frag reads: row r = wc*64 + nj*16 + l15 (r&7 == l15&7);
  // slot(ks=0) = l4 ^ (l15&7); slot(ks=1) = slot0 ^ 4  =>  addr ^ 64.
  const unsigned b_lane = (unsigned)((wc * 64 + l15) * 128) +
                          (unsigned)((l4 ^ (l15 & 7)) << 4);

  i32x4 acc[8][4] = {};
  i32x4 aE[8], aO[8], b0[4], b1[4];

#define SB __builtin_amdgcn_sched_barrier(0)

  // prologue: B(0) staged, A'(0) ks0 in flight
  ISSUE_B(0);
  SB;
  LOAD_A(aE, 0, 0);
  SB;

#pragma unroll 1
  for (int kt = 0; kt < NTILE; ++kt) {
    // tile-top: g2l B(kt) landed (A' loads may stay in flight), all waves sync
    asm volatile("s_waitcnt vmcnt(8)" ::: "memory");
    __builtin_amdgcn_s_barrier();
    SB;

    const signed char* Bb = lds + (unsigned)(kt & 1) * BBUF;
    // ds_read all 8 B-frags for this tile (compiler inserts exact lgkm waits)
#pragma unroll
    for (int nj = 0; nj < 4; ++nj) {
      b0[nj] = *(const i32x4*)(Bb + (b_lane + nj * 2048));
      b1[nj] = *(const i32x4*)(Bb + ((b_lane + nj * 2048) ^ 64u));
    }
    SB;
    // A' ks1 of this tile — lands under the ks0 MFMA cluster
    LOAD_A(aO, kt, 1);
    SB;
    // stage B(kt+1) into the other buffer (WAR-safe: its readers drained
    // before the barrier above, since their MFMAs consumed them)
    if (kt + 1 < NTILE) ISSUE_B(kt + 1);
    SB;

    __builtin_amdgcn_s_setprio(1);
#pragma unroll
    for (int mi = 0; mi < 8; ++mi)
#pragma unroll
      for (int nj = 0; nj < 4; ++nj)
        acc[mi][nj] = __builtin_amdgcn_mfma_i32_16x16x64_i8(aE[mi], b0[nj], acc[mi][nj], 0, 0, 0);
    __builtin_amdgcn_s_setprio(0);
    SB;
    // A' ks0 of next tile — lands under the ks1 MFMA cluster
    if (kt + 1 < NTILE) LOAD_A(aE, kt + 1, 0);
    SB;
    __builtin_amdgcn_s_setprio(1);
#pragma unroll
    for (int mi = 0; mi < 8; ++mi)
#pragma unroll
      for (int nj = 0; nj < 4; ++nj)
        acc[mi][nj] = __builtin_amdgcn_mfma_i32_16x16x64_i8(aO[mi], b1[nj], acc[mi][nj], 0, 0, 0);
    __builtin_amdgcn_s_setprio(0);
    SB;
  }

  // epilogue: C/D layout col=lane&15, row=(lane>>4)*4+reg [m89, dtype-indep]
  const float cs = scale[0] * xscale[0];
#pragma unroll
  for (int nj = 0; nj < 4; ++nj) {
    const int n = n0 + wc * 64 + nj * 16 + l15;
    const float bj = bias[n];
#pragma unroll
    for (int mi = 0; mi < 8; ++mi) {
      const int m = m0 + wr * 128 + mi * 16 + l4 * 4;
      float* o = out + (size_t)m * NDIM + n;
#pragma unroll
      for (int v = 0; v < 4; ++v)
        o[(size_t)v * NDIM] = (float)acc[mi][nj][v] * cs + bj;
    }
  }
#undef ISSUE_B
#undef LOAD_A
#undef SB
}

extern "C" void kernel_launch(void* const* d_in, const int* in_sizes, int n_in,
                              void* d_out, int out_size, void* d_ws, size_t ws_size,
                              hipStream_t stream) {
  const float* x = (const float*)d_in[0];
  const void* w = d_in[1];
  const float* scale = (const float*)d_in[2];
  const float* xscale = (const float*)d_in[3];
  const float* bias = (const float*)d_in[4];
  float* out = (float*)d_out;

  const int M = in_sizes[0] / KDIM;  // 8192

  int* flag = (int*)d_ws;
  signed char* wq = (signed char*)d_ws + 256;
  signed char* aq = wq + (size_t)NDIM * KDIM;  // A' fragment layout, M*K bytes

  const size_t need = 256 + (size_t)NDIM * KDIM + (size_t)M * KDIM;
  if (ws_size < need) return;

  w8l_detect<<<1, 256, 0, stream>>>((const int*)w, flag);
  w8l_pack<<<(NDIM * KDIM / 16) / 256, 256, 0, stream>>>(w, flag, wq);
  w8l_quant<<<(M * KDIM / 16) / 256, 256, 0, stream>>>(x, xscale, aq);

  const int nbn = NDIM / BN;  // 16
  w8l_gemm<<<(M / BM) * nbn, 512, 0, stream>>>(
      aq, (const signed char*)w, wq, flag, scale, xscale, bias, out, nbn);
}

// Round 11
// 198.958 us; speedup vs baseline: 1.2737x; 1.0140x over previous
//
#include <hip/hip_runtime.h>

#define KDIM 4096
#define NDIM 4096
#define BM 256
#define BN 256
#define BK 128            // K bytes (int8) per tile
#define NTILE (KDIM / BK) // 32

using i32x4 = __attribute__((ext_vector_type(4))) int;
using i32x16 = __attribute__((ext_vector_type(16))) int;

__device__ __forceinline__ void g2l16(const void* g, void* l) {
  __builtin_amdgcn_global_load_lds(
      (const __attribute__((address_space(1))) void*)g,
      (__attribute__((address_space(3))) void*)l,
      16, 0, 0);
}

// ---------------- detect: weight buffer int32-expanded (flag=1) or raw int8 (flag=0)?
__global__ void w8l_detect(const int* __restrict__ w32, int* __restrict__ flag) {
  __shared__ int s;
  const int t = threadIdx.x;
  if (t == 0) s = 1;
  __syncthreads();
  bool oob = false;
#pragma unroll
  for (int i = 0; i < 16; ++i) {
    int v = w32[t * 16 + i];
    if (v < -128 || v > 127) oob = true;
  }
  if (oob) atomicAnd(&s, 0);
  __syncthreads();
  if (t == 0) *flag = s;
}

// ---------------- pack int32 weights to int8 (no-op when flag==0)
__global__ void w8l_pack(const void* __restrict__ wsrc, const int* __restrict__ flag,
                         signed char* __restrict__ wq) {
  if (*flag == 0) return;
  const int t = blockIdx.x * blockDim.x + threadIdx.x;
  const int4* s = (const int4*)wsrc;
  int4 a = s[t * 4 + 0], b = s[t * 4 + 1], c = s[t * 4 + 2], d = s[t * 4 + 3];
  int4 o;
  o.x = (a.x & 255) | ((a.y & 255) << 8) | ((a.z & 255) << 16) | ((a.w & 255) << 24);
  o.y = (b.x & 255) | ((b.y & 255) << 8) | ((b.z & 255) << 16) | ((b.w & 255) << 24);
  o.z = (c.x & 255) | ((c.y & 255) << 8) | ((c.z & 255) << 16) | ((c.w & 255) << 24);
  o.w = (d.x & 255) | ((d.y & 255) << 8) | ((d.z & 255) << 16) | ((d.w & 255) << 24);
  ((int4*)wq)[t] = o;
}

// ---------------- quantize activations: 16 floats / thread (row-major A)
__global__ void w8l_quant(const float* __restrict__ x, const float* __restrict__ xs,
                          signed char* __restrict__ xq) {
  const int t = blockIdx.x * blockDim.x + threadIdx.x;
  const float s = *xs;
  const float4* x4 = (const float4*)x;
  int4 o;
  int* op = (int*)&o;
#pragma unroll
  for (int q = 0; q < 4; ++q) {
    float4 f = x4[t * 4 + q];
    int v0 = __float2int_rn(f.x / s);
    int v1 = __float2int_rn(f.y / s);
    int v2 = __float2int_rn(f.z / s);
    int v3 = __float2int_rn(f.w / s);
    v0 = v0 < -128 ? -128 : (v0 > 127 ? 127 : v0);
    v1 = v1 < -128 ? -128 : (v1 > 127 ? 127 : v1);
    v2 = v2 < -128 ? -128 : (v2 > 127 ? 127 : v2);
    v3 = v3 < -128 ? -128 : (v3 > 127 ? 127 : v3);
    op[q] = (v0 & 255) | ((v1 & 255) << 8) | ((v2 & 255) << 16) | ((v3 & 255) << 24);
  }
  ((int4*)xq)[t] = o;
}

// ---------------- 256x256 i8 GEMM, m201-style lockstep phases, 32x32x32 MFMA.
// 4 phases per K-tile, each: {6 ds_read (all 8 waves burst -> LDS at full BW)
// -> stage g2l -> barrier -> lgkm(0) -> setprio MFMA x8 -> barrier}.
// Staging of tile t+1 front-loaded in phases 0-1 of tile t; boundary vmcnt(0)
// at phase 3 waits for loads issued ~2 phases (~1900 cyc) earlier -> no stall.
// WAR: buf (t+1)&1's readers (tile t-1) drained at t-1's final lgkm+barrier.
// Swizzle (r7-verified, 0 conflicts): LDS(r,slot)=chunk (slot ^ ((r^(r>>3))&7)).
__global__ __launch_bounds__(512, 2) void w8l_gemm(
    const signed char* __restrict__ Aq,
    const signed char* __restrict__ Wraw, const signed char* __restrict__ Wpk,
    const int* __restrict__ flag,
    const float* __restrict__ scale, const float* __restrict__ xscale,
    const float* __restrict__ bias, float* __restrict__ out, int nbn) {
  __shared__ signed char lds[131072];  // 2 bufs x (A 32K + B 32K)

  const signed char* __restrict__ Wq = (*flag) ? Wpk : Wraw;

  const int tid = threadIdx.x;
  const int lane = tid & 63;
  const int wid = tid >> 6;  // 0..7
  const int wr = wid >> 2;   // 0..1 (wave rows: 128)
  const int wc = wid & 3;    // 0..3 (wave cols: 64)
  const int l31 = lane & 31;
  const int l5 = lane >> 5;  // 0..1 k-half

  // XCD-aware bijective swizzle (grid = 512, divisible by 8)
  const int nwg = gridDim.x;
  const int cpx = nwg >> 3;
  const int bid = blockIdx.x;
  const int swz = (bid & 7) * cpx + (bid >> 3);
  const int bm = swz / nbn, bn = swz % nbn;
  const int m0 = bm * BM, n0 = bn * BN;

  // staging: one g2l16 issue = 512 thr x 16 B = 8 KB = 64 rows x 128 B
  const unsigned r_in = (unsigned)tid >> 3;  // 0..63 (s(r) invariant under +64)
  const unsigned c16 = (unsigned)tid & 7;
  const unsigned s_r = (r_in ^ (r_in >> 3)) & 7u;
  const unsigned swcol = ((c16 ^ s_r) << 4);
  const signed char* agp = Aq + (size_t)(m0 + r_in) * KDIM + swcol;
  const signed char* wgp = Wq + (size_t)(n0 + r_in) * KDIM + swcol;
  const unsigned ldsoff = (unsigned)tid * 16u;

#define ISSUE_A(t)                                                           \
  do {                                                                       \
    const size_t koff_ = (size_t)(t) * BK;                                   \
    signed char* lb_ = lds + (unsigned)((t) & 1) * 65536u + ldsoff;          \
    _Pragma("unroll") for (int u = 0; u < 4; ++u)                            \
      g2l16(agp + (size_t)(u * 64) * KDIM + koff_, lb_ + u * 8192);          \
  } while (0)
#define ISSUE_B(t)                                                           \
  do {                                                                       \
    const size_t koff_ = (size_t)(t) * BK;                                   \
    signed char* lb_ = lds + (unsigned)((t) & 1) * 65536u + 32768u + ldsoff; \
    _Pragma("unroll") for (int u = 0; u < 4; ++u)                            \
      g2l16(wgp + (size_t)(u * 64) * KDIM + koff_, lb_ + u * 8192);          \
  } while (0)

  // 32x32x32 frags: lane = row l31, chunk = 2*ks + l5, slot = chunk ^ s(r)
#define RD(base, ks)                                                         \
  do {                                                                       \
    _Pragma("unroll") for (int mi = 0; mi < 4; ++mi) {                       \
      const int r_ = wr * 128 + mi * 32 + l31;                               \
      const int sx_ = (r_ ^ (r_ >> 3)) & 7;                                  \
      af[mi] = *(const i32x4*)((base) + r_ * 128 +                           \
                               ((((ks) * 2 + l5) ^ sx_) << 4));              \
    }                                                                        \
    _Pragma("unroll") for (int nj = 0; nj < 2; ++nj) {                       \
      const int r_ = wc * 64 + nj * 32 + l31;                                \
      const int sx_ = (r_ ^ (r_ >> 3)) & 7;                                  \
      bf[nj] = *(const i32x4*)((base) + 32768 + r_ * 128 +                   \
                               ((((ks) * 2 + l5) ^ sx_) << 4));              \
    }                                                                        \
  } while (0)

#define SB __builtin_amdgcn_sched_barrier(0)

#define MFMA8                                                                \
  __builtin_amdgcn_s_setprio(1);                                             \
  _Pragma("unroll") for (int mi = 0; mi < 4; ++mi)                           \
      _Pragma("unroll") for (int nj = 0; nj < 2; ++nj)                       \
          acc[mi][nj] = __builtin_amdgcn_mfma_i32_32x32x32_i8(               \
              af[mi], bf[nj], acc[mi][nj], 0, 0, 0);                         \
  __builtin_amdgcn_s_setprio(0);

  i32x16 acc[4][2] = {};
  i32x4 af[4], bf[2];

  // prologue: tile 0 staged, drained (one-time ~900 cyc)
  ISSUE_A(0);
  ISSUE_B(0);
  asm volatile("s_waitcnt vmcnt(0)" ::: "memory");
  __builtin_amdgcn_s_barrier();
  SB;

#pragma unroll 1
  for (int kt = 0; kt < NTILE; ++kt) {
    const signed char* base = lds + (unsigned)(kt & 1) * 65536u;

    // ---- phase 0: reads ks0 ; stage A(kt+1)
    RD(base, 0);
    SB;
    if (kt + 1 < NTILE) ISSUE_A(kt + 1);
    SB;
    __builtin_amdgcn_s_barrier();
    asm volatile("s_waitcnt lgkmcnt(0)" ::: "memory");
    SB;
    MFMA8;
    SB;
    __builtin_amdgcn_s_barrier();

    // ---- phase 1: reads ks1 ; stage B(kt+1)
    RD(base, 1);
    SB;
    if (kt + 1 < NTILE) ISSUE_B(kt + 1);
    SB;
    __builtin_amdgcn_s_barrier();
    asm volatile("s_waitcnt lgkmcnt(0)" ::: "memory");
    SB;
    MFMA8;
    SB;
    __builtin_amdgcn_s_barrier();

    // ---- phase 2: reads ks2
    RD(base, 2);
    SB;
    __builtin_amdgcn_s_barrier();
    asm volatile("s_waitcnt lgkmcnt(0)" ::: "memory");
    SB;
    MFMA8;
    SB;
    __builtin_amdgcn_s_barrier();

    // ---- phase 3: reads ks3 ; boundary vmcnt(0) (stages issued 2 phases ago)
    RD(base, 3);
    SB;
    asm volatile("s_waitcnt vmcnt(0)" ::: "memory");
    __builtin_amdgcn_s_barrier();
    asm volatile("s_waitcnt lgkmcnt(0)" ::: "memory");
    SB;
    MFMA8;
    SB;
    __builtin_amdgcn_s_barrier();
  }

  // epilogue: 32x32 C/D layout col=lane&31, row=(reg&3)+8*(reg>>2)+4*(lane>>5)
  // [m74/m101-verified, dtype-independent; r7-passed code]
  const float cs = scale[0] * xscale[0];
#pragma unroll
  for (int nj = 0; nj < 2; ++nj) {
    const int n = n0 + wc * 64 + nj * 32 + l31;
    const float bj = bias[n];
#pragma unroll
    for (int mi = 0; mi < 4; ++mi) {
      const int mbase = m0 + wr * 128 + mi * 32 + l5 * 4;
#pragma unroll
      for (int r = 0; r < 16; ++r) {
        const int m = mbase + (r & 3) + 8 * (r >> 2);
        out[(size_t)m * NDIM + n] = (float)acc[mi][nj][r] * cs + bj;
      }
    }
  }
#undef ISSUE_A
#undef ISSUE_B
#undef RD
#undef MFMA8
#undef SB
}

extern "C" void kernel_launch(void* const* d_in, const int* in_sizes, int n_in,
                              void* d_out, int out_size, void* d_ws, size_t ws_size,
                              hipStream_t stream) {
  const float* x = (const float*)d_in[0];
  const void* w = d_in[1];
  const float* scale = (const float*)d_in[2];
  const float* xscale = (const float*)d_in[3];
  const float* bias = (const float*)d_in[4];
  float* out = (float*)d_out;

  const int M = in_sizes[0] / KDIM;  // 8192

  int* flag = (int*)d_ws;
  signed char* wq = (signed char*)d_ws + 256;
  signed char* aq = wq + (size_t)NDIM * KDIM;

  const size_t need = 256 + (size_t)NDIM * KDIM + (size_t)M * KDIM;
  if (ws_size < need) return;

  w8l_detect<<<1, 256, 0, stream>>>((const int*)w, flag);
  w8l_pack<<<(NDIM * KDIM / 16) / 256, 256, 0, stream>>>(w, flag, wq);
  w8l_quant<<<(M * KDIM / 16) / 256, 256, 0, stream>>>(x, xscale, aq);

  const int nbn = NDIM / BN;  // 16
  w8l_gemm<<<(M / BM) * nbn, 512, 0, stream>>>(
      aq, (const signed char*)w, wq, flag, scale, xscale, bias, out, nbn);
}